// Round 19
// baseline (776.282 us; speedup 1.0000x reference)
//
#include <hip/hip_runtime.h>
#include <math.h>

#define H 64
#define VOCABN 64
#define LSEQ 2048
#define LN_EPS 1e-5f

// ---------- generic DPP add helper ----------
template <int CTRL>
__device__ __forceinline__ float dpp_add(float x) {
  return x + __int_as_float(__builtin_amdgcn_update_dpp(
      0, __float_as_int(x), CTRL, 0xF, 0xF, true));
}

// all-lane sum with broadcast result (tables / readout only)
__device__ __forceinline__ float wave_allsum(float x) {
  x = dpp_add<0xB1>(x);   // quad_perm [1,0,3,2]
  x = dpp_add<0x4E>(x);   // quad_perm [2,3,0,1]
  x = dpp_add<0x141>(x);  // row_half_mirror
  x = dpp_add<0x140>(x);  // row_mirror
  x += __shfl_xor(x, 16, 64);
  x += __shfl_xor(x, 32, 64);
  return x;
}

// all-VALU wave64 reduction: lane 63 holds the total (rounds 3/7-18 validated)
__device__ __forceinline__ float reduce_to_lane63(float x) {
  x = dpp_add<0x111>(x);  // row_shr:1
  x = dpp_add<0x112>(x);  // row_shr:2
  x = dpp_add<0x114>(x);  // row_shr:4
  x = dpp_add<0x118>(x);  // row_shr:8
  x = dpp_add<0x142>(x);  // row_bcast:15
  x = dpp_add<0x143>(x);  // row_bcast:31
  return x;
}

__device__ __forceinline__ float rdlf(float v, int lane) {
  return __int_as_float(__builtin_amdgcn_readlane(__float_as_int(v), lane));
}

// norm: sqrt of wave-total of x*x, uniform scalar (bitwise == r13's gate math)
__device__ __forceinline__ float wave_norm63(float x) {
  float nd2 = reduce_to_lane63(x * x);
  return sqrtf(rdlf(nd2, 63));
}

// ---------------- Kernel A: per-token tables (verbatim rounds 7-18, passed) ----------------
__global__ __launch_bounds__(64) void tables_kernel(
    const float* __restrict__ embed, const float* __restrict__ W1, const float* __restrict__ b1,
    const float* __restrict__ W2, const float* __restrict__ b2,
    const float* __restrict__ ln_g, const float* __restrict__ ln_b,
    const float* __restrict__ Wk, const float* __restrict__ Wv,
    float* __restrict__ Htab, float* __restrict__ Ktab, float* __restrict__ Vtab,
    float* __restrict__ nvtab)
{
  __shared__ float hs[H];
  __shared__ float ff1[2 * H];
  __shared__ float lns[H];
  const int c = blockIdx.x;
  const int i = threadIdx.x;

  float e = embed[c * H + i];
  hs[i] = e;
  __syncthreads();

  float r1 = b1[i], r2 = b1[i + H];
  for (int j = 0; j < H; ++j) {
    float hj = hs[j];
    r1 = fmaf(W1[i * H + j], hj, r1);
    r2 = fmaf(W1[(i + H) * H + j], hj, r2);
  }
  ff1[i]     = fmaxf(r1, 0.f);
  ff1[i + H] = fmaxf(r2, 0.f);
  __syncthreads();

  float o = b2[i];
  for (int m = 0; m < 2 * H; ++m) o = fmaf(W2[i * 2 * H + m], ff1[m], o);
  float y = e + o;

  float mu  = wave_allsum(y) * (1.f / H);
  float d   = y - mu;
  float var = wave_allsum(d * d) * (1.f / H);
  float ln  = d * (1.f / sqrtf(var + LN_EPS)) * ln_g[i] + ln_b[i];
  lns[i] = ln;
  __syncthreads();
  Htab[c * H + i] = ln;

  float k = 0.f, v = 0.f;
  for (int j = 0; j < H; ++j) {
    float lj = lns[j];
    k = fmaf(Wk[i * H + j], lj, k);
    v = fmaf(Wv[i * H + j], lj, v);
  }
  float nk = sqrtf(wave_allsum(k * k));
  Ktab[c * H + i] = k / fmaxf(nk, 1e-12f);
  Vtab[c * H + i] = v;
  float nv = sqrtf(wave_allsum(v * v));
  if (i == 0) nvtab[c] = 0.4f * nv;   // gate threshold, sqrt domain
}

// ---------------- Kernel B: 4-wave eager scan, static-stream prefetch, norm pipeline ----------------
// Round-13 structure (best, 576us) + 3 latency removals:
//  (1) forwarding coeffs gs1..gs4[t] = G[x[t]][x[t+k]] and thseq[t] precomputed at staging
//      (token stream static) -> stride-1 prefetched, no same-step Gram pointer-chase;
//  (2) RMW G-row / K-row slices prefetched one step ahead (static tables, race-free);
//  (3) per-row norms computed once at pipeline entry (3-step slack); on accept only the
//      3 forwarded rows' norms recomputed (9-op DPP chains, overlap barrier+RMW).
// All fmaf operands / DPP chains / compares identical to rounds 10-13 -> bitwise output.
__global__ __launch_bounds__(256, 1) void scan_kernel(
    const int* __restrict__ x, const float* __restrict__ Htab,
    const float* __restrict__ Ktab, const float* __restrict__ Vtab,
    const float* __restrict__ nvtab,
    const float* __restrict__ Wq, const float* __restrict__ Wr,
    const float* __restrict__ alpha, const float* __restrict__ Wout,
    const float* __restrict__ bout, float* __restrict__ out)
{
  __shared__ float4 Kl4[VOCABN * H / 4];   // khat [c][j]; becomes M_N after scan
  __shared__ float  Gl[VOCABN * H];        // Gram [c][cc] (static after init)
  __shared__ float4 Rl4[VOCABN * H / 4];   // residual [c][i]
  __shared__ int    xl[LSEQ];
  __shared__ float  thseq[LSEQ];           // thl[x[t]]
  __shared__ float  aux[4 * LSEQ];         // gs1..gs4; reused as M_T at readout
  __shared__ float  thl[VOCABN];
  __shared__ float  hbuf[H];
  __shared__ float  qbuf[H];
  __shared__ float  mbuf[H];
  float* Kl  = (float*)Kl4;
  float* Rl  = (float*)Rl4;
  float* gs1 = aux;
  float* gs2 = aux + LSEQ;
  float* gs3 = aux + 2 * LSEQ;
  float* gs4 = aux + 3 * LSEQ;

  const int b    = blockIdx.x;
  const int tid  = threadIdx.x;
  const int lane = tid & 63;
  const int wid  = tid >> 6;

  // ---- stage tables + token row into LDS (256 threads) ----
  {
    const float4* Kg = (const float4*)Ktab;
    const float4* Vg = (const float4*)Vtab;
    for (int q = tid; q < VOCABN * H / 4; q += 256) { Kl4[q] = Kg[q]; Rl4[q] = Vg[q]; }
    const int4* xg = (const int4*)(x + b * LSEQ);
    int4* xl4 = (int4*)xl;
    for (int q = tid; q < LSEQ / 4; q += 256) xl4[q] = xg[q];
    if (tid < VOCABN) thl[tid] = nvtab[tid];
  }
  __syncthreads();

  // ---- Gram in LDS, 16 rows per wave (verbatim rounds 10-13) ----
  {
    float4 kr[16];
#pragma unroll
    for (int q = 0; q < 16; ++q) kr[q] = Kl4[lane * 16 + q];
    for (int r = 0; r < 16; ++r) {
      const int c2 = wid * 16 + r;
      const float4* kp2 = (const float4*)(Kl + c2 * H);
      float a0 = 0.f, a1 = 0.f, a2 = 0.f, a3 = 0.f;
#pragma unroll
      for (int q = 0; q < 16; ++q) {
        float4 kq = kp2[q];
        a0 = fmaf(kr[q].x, kq.x, a0);
        a1 = fmaf(kr[q].y, kq.y, a1);
        a2 = fmaf(kr[q].z, kq.z, a2);
        a3 = fmaf(kr[q].w, kq.w, a3);
      }
      Gl[c2 * H + lane] = (a0 + a1) + (a2 + a3);
    }
  }
  __syncthreads();

  // ---- per-step forwarding coefficients + threshold stream (one-time) ----
  for (int t = tid; t < LSEQ; t += 256) {
    const int a  = xl[t];
    const int i1 = (t + 1 < LSEQ) ? t + 1 : LSEQ - 1;
    const int i2 = (t + 2 < LSEQ) ? t + 2 : LSEQ - 1;
    const int i3 = (t + 3 < LSEQ) ? t + 3 : LSEQ - 1;
    const int i4 = (t + 4 < LSEQ) ? t + 4 : LSEQ - 1;
    gs1[t] = Gl[a * H + xl[i1]];
    gs2[t] = Gl[a * H + xl[i2]];
    gs3[t] = Gl[a * H + xl[i3]];
    gs4[t] = Gl[a * H + xl[i4]];
    thseq[t] = thl[a];
  }
  __syncthreads();

  // M column slice: Mw[q] holds M[lane][wid*16 + 4q .. 4q+3]
  float4 Mw[4];
#pragma unroll
  for (int q = 0; q < 4; ++q) Mw[q] = make_float4(0.f, 0.f, 0.f, 0.f);

  // ---- depth-4 pipeline fill ----
  int c0 = xl[0], c1 = xl[1], c2 = xl[2], c3 = xl[3];
  float r0 = Rl[c0 * H + lane];
  float r1 = Rl[c1 * H + lane];
  float r2 = Rl[c2 * H + lane];
  float r3 = Rl[c3 * H + lane];
  float n0 = wave_norm63(r0);
  float n1 = wave_norm63(r1);
  float n2 = wave_norm63(r2);
  float th0 = thseq[0];
  float g1 = gs1[0], g2 = gs2[0], g3 = gs3[0], g4 = gs4[0];
  // RMW/M slices for c0 (used only on accept at t=0)
  float4 gA, gB, gC, gD, kA, kB, kC, kD;
  {
    const float4* gpp = ((const float4*)(Gl + c0 * H)) + wid * 4;
    const float4* kpp = ((const float4*)(Kl + c0 * H)) + wid * 4;
    gA = gpp[0]; gB = gpp[1]; gC = gpp[2]; gD = gpp[3];
    kA = kpp[0]; kB = kpp[1]; kC = kpp[2]; kD = kpp[3];
  }

  for (int t = 0; t < LSEQ; ++t) {
    const int i4x = (t + 4 < LSEQ) ? t + 4 : LSEQ - 1;
    const int i1x = (t + 1 < LSEQ) ? t + 1 : LSEQ - 1;
    const int c4  = xl[i4x];
    float r4 = Rl[c4 * H + lane];          // pre-accept value (waitcnt before barrier)
    float n3 = wave_norm63(r3);            // entry norm (1-step-old data, 3-step slack)
    float thn = thseq[i1x];
    float gn1 = gs1[i1x], gn2 = gs2[i1x], gn3 = gs3[i1x], gn4 = gs4[i1x];

    const float thu = __int_as_float(__builtin_amdgcn_readfirstlane(__float_as_int(th0)));

    if (n0 > thu) {                        // block-uniform accept
      const float delta = r0;
      // in-register forwarding with precomputed coefficients (bitwise == RMW values)
      r1 = fmaf(-g1, delta, r1);
      r2 = fmaf(-g2, delta, r2);
      r3 = fmaf(-g3, delta, r3);
      n1 = wave_norm63(r1);                // 9-op chains, overlap barrier/RMW below
      n2 = wave_norm63(r2);
      n3 = wave_norm63(r3);
      __syncthreads();                     // read-fence
      // RMW 16 rows/wave with prefetched G slice
      float gsl[16] = {gA.x, gA.y, gA.z, gA.w, gB.x, gB.y, gB.z, gB.w,
                       gC.x, gC.y, gC.z, gC.w, gD.x, gD.y, gD.z, gD.w};
#pragma unroll
      for (int r = 0; r < 16; ++r) {
        const int cc = wid * 16 + r;
        Rl[cc * H + lane] = fmaf(-gsl[r], delta, Rl[cc * H + lane]);
      }
      // M column slice with prefetched K slice (16 FMA)
      Mw[0].x = fmaf(delta, kA.x, Mw[0].x);
      Mw[0].y = fmaf(delta, kA.y, Mw[0].y);
      Mw[0].z = fmaf(delta, kA.z, Mw[0].z);
      Mw[0].w = fmaf(delta, kA.w, Mw[0].w);
      Mw[1].x = fmaf(delta, kB.x, Mw[1].x);
      Mw[1].y = fmaf(delta, kB.y, Mw[1].y);
      Mw[1].z = fmaf(delta, kB.z, Mw[1].z);
      Mw[1].w = fmaf(delta, kB.w, Mw[1].w);
      Mw[2].x = fmaf(delta, kC.x, Mw[2].x);
      Mw[2].y = fmaf(delta, kC.y, Mw[2].y);
      Mw[2].z = fmaf(delta, kC.z, Mw[2].z);
      Mw[2].w = fmaf(delta, kC.w, Mw[2].w);
      Mw[3].x = fmaf(delta, kD.x, Mw[3].x);
      Mw[3].y = fmaf(delta, kD.y, Mw[3].y);
      Mw[3].z = fmaf(delta, kD.z, Mw[3].z);
      Mw[3].w = fmaf(delta, kD.w, Mw[3].w);
      __syncthreads();                     // write-fence
      r4 = fmaf(-g4, delta, r4);           // r4 held pre-accept value -> forward
    }

    // bottom: prefetch RMW/M slices for next gate token c1 (static tables)
    {
      const float4* gpn = ((const float4*)(Gl + c1 * H)) + wid * 4;
      const float4* kpn = ((const float4*)(Kl + c1 * H)) + wid * 4;
      gA = gpn[0]; gB = gpn[1]; gC = gpn[2]; gD = gpn[3];
      kA = kpn[0]; kB = kpn[1]; kC = kpn[2]; kD = kpn[3];
    }
    // shift
    r0 = r1; r1 = r2; r2 = r3; r3 = r4;
    n0 = n1; n1 = n2; n2 = n3;
    c0 = c1; c1 = c2; c2 = c3; c3 = c4;
    th0 = thn; g1 = gn1; g2 = gn2; g3 = gn3; g4 = gn4;
  }

  // ---- reassemble M: aux = M_T (stride H), Kl = M_N (verbatim rounds 12/13 layout) ----
  __syncthreads();
  float* Mt = aux;                          // gs arrays dead; 4096 floats needed
#pragma unroll
  for (int r = 0; r < 4; ++r) {
    const int jb = wid * 16 + r * 4;
    float4 m = Mw[r];
    Mt[(jb + 0) * H + lane] = m.x;
    Mt[(jb + 1) * H + lane] = m.y;
    Mt[(jb + 2) * H + lane] = m.z;
    Mt[(jb + 3) * H + lane] = m.w;
    Kl[lane * H + jb + 0] = m.x;
    Kl[lane * H + jb + 1] = m.y;
    Kl[lane * H + jb + 2] = m.z;
    Kl[lane * H + jb + 3] = m.w;
  }
  __syncthreads();

  // ---------------- fused readout: wave 0 (verbatim rounds 12/13, passed) ----------------
  if (wid == 0) {
    const int clast = xl[LSEQ - 1];
    hbuf[lane] = Htab[clast * H + lane];

    float qi = 0.f;
    for (int j = 0; j < H; ++j) qi = fmaf(Wq[lane * H + j], hbuf[j], qi);
    qbuf[lane] = qi;

    float qri = 0.f;
    for (int j = 0; j < H; ++j) qri = fmaf(Wr[lane * H + j], qbuf[j], qri);

    // slot norms^2: lane s reads M_N column s (conflict-free)
    float n2r = 0.f;
    for (int i2 = 0; i2 < H; ++i2) { float m = Kl[i2 * H + lane]; n2r = fmaf(m, m, n2r); }

    // top-8 slots by norm (ties -> smaller index)
    const int KS = 8;
    int idxs[KS];
    float nloc = n2r;
#pragma unroll
    for (int k = 0; k < KS; ++k) {
      float v = nloc; int idx = lane;
#pragma unroll
      for (int s = 1; s < 64; s <<= 1) {
        float ov = __shfl_xor(v, s, 64);
        int   oi = __shfl_xor(idx, s, 64);
        if (ov > v || (ov == v && oi < idx)) { v = ov; idx = oi; }
      }
      idxs[k] = idx;
      if (lane == idx) nloc = -1.f;
    }

    float sel[KS], lg[KS];
#pragma unroll
    for (int k = 0; k < KS; ++k) {
      float s = Mt[idxs[k] * H + lane];     // M_T[idx][lane]
      sel[k] = s;
      lg[k] = wave_allsum(s * qri) * 0.125f;   // / sqrt(64)
    }
    float lmax = lg[0];
#pragma unroll
    for (int k = 1; k < KS; ++k) lmax = fmaxf(lmax, lg[k]);
    float esum = 0.f, retro = 0.f;
#pragma unroll
    for (int k = 0; k < KS; ++k) {
      float e = expf(lg[k] - lmax);
      esum += e;
      retro = fmaf(e, sel[k], retro);
    }
    retro /= esum;

    // m_ctx = M q : lane i, ascending j reading M_T[j][lane] (conflict-free)
    float mc = 0.f;
    for (int j = 0; j < H; ++j) mc = fmaf(Mt[j * H + lane], qbuf[j], mc);

    float a = 1.f / (1.f + expf(-alpha[0]));
    float mixed = fmaxf(fmaf(a, retro, (1.f - a) * mc), 0.f);
    mbuf[lane] = mixed;

    float oo = bout[lane];
    for (int i2 = 0; i2 < H; ++i2) oo = fmaf(Wout[lane * H + i2], mbuf[i2], oo);
    out[b * VOCABN + lane] = oo;
  }
}

extern "C" void kernel_launch(void* const* d_in, const int* in_sizes, int n_in,
                              void* d_out, int out_size, void* d_ws, size_t ws_size,
                              hipStream_t stream) {
  const int*   x     = (const int*)d_in[0];
  const float* embed = (const float*)d_in[1];
  const float* W1    = (const float*)d_in[2];
  const float* b1    = (const float*)d_in[3];
  const float* W2    = (const float*)d_in[4];
  const float* b2    = (const float*)d_in[5];
  const float* ln_g  = (const float*)d_in[6];
  const float* ln_b  = (const float*)d_in[7];
  const float* Wk    = (const float*)d_in[8];
  const float* Wv    = (const float*)d_in[9];
  const float* Wq    = (const float*)d_in[10];
  const float* Wr    = (const float*)d_in[11];
  const float* alpha = (const float*)d_in[12];
  const float* Wout  = (const float*)d_in[13];
  const float* bout  = (const float*)d_in[14];
  float* out = (float*)d_out;

  const int B = in_sizes[0] / LSEQ;

  float* ws    = (float*)d_ws;
  float* Htab  = ws;          // 4096
  float* Ktab  = ws + 4096;   // 4096
  float* Vtab  = ws + 8192;   // 4096
  float* nvtab = ws + 12288;  // 64

  tables_kernel<<<VOCABN, 64, 0, stream>>>(embed, W1, b1, W2, b2, ln_g, ln_b,
                                           Wk, Wv, Htab, Ktab, Vtab, nvtab);
  scan_kernel<<<B, 256, 0, stream>>>(x, Htab, Ktab, Vtab, nvtab,
                                     Wq, Wr, alpha, Wout, bout, out);
}

// Round 20
// 567.759 us; speedup vs baseline: 1.3673x; 1.3673x over previous
//
#include <hip/hip_runtime.h>
#include <math.h>

#define H 64
#define VOCABN 64
#define LSEQ 2048
#define LN_EPS 1e-5f
#define TCH 8
#define NCHUNK (LSEQ / TCH)   // 256

// ---------- generic DPP add helper ----------
template <int CTRL>
__device__ __forceinline__ float dpp_add(float x) {
  return x + __int_as_float(__builtin_amdgcn_update_dpp(
      0, __float_as_int(x), CTRL, 0xF, 0xF, true));
}

// all-lane sum with broadcast result (tables / readout only)
__device__ __forceinline__ float wave_allsum(float x) {
  x = dpp_add<0xB1>(x);   // quad_perm [1,0,3,2]
  x = dpp_add<0x4E>(x);   // quad_perm [2,3,0,1]
  x = dpp_add<0x141>(x);  // row_half_mirror
  x = dpp_add<0x140>(x);  // row_mirror
  x += __shfl_xor(x, 16, 64);
  x += __shfl_xor(x, 32, 64);
  return x;
}

// all-VALU wave64 reduction: lane 63 holds the total (rounds 3/7-19 validated)
__device__ __forceinline__ float reduce_to_lane63(float x) {
  x = dpp_add<0x111>(x);  // row_shr:1
  x = dpp_add<0x112>(x);  // row_shr:2
  x = dpp_add<0x114>(x);  // row_shr:4
  x = dpp_add<0x118>(x);  // row_shr:8
  x = dpp_add<0x142>(x);  // row_bcast:15
  x = dpp_add<0x143>(x);  // row_bcast:31
  return x;
}

__device__ __forceinline__ float rdlf(float v, int lane) {
  return __int_as_float(__builtin_amdgcn_readlane(__float_as_int(v), lane));
}

// ---------------- Kernel A: per-token tables (verbatim rounds 7-19, passed) ----------------
__global__ __launch_bounds__(64) void tables_kernel(
    const float* __restrict__ embed, const float* __restrict__ W1, const float* __restrict__ b1,
    const float* __restrict__ W2, const float* __restrict__ b2,
    const float* __restrict__ ln_g, const float* __restrict__ ln_b,
    const float* __restrict__ Wk, const float* __restrict__ Wv,
    float* __restrict__ Htab, float* __restrict__ Ktab, float* __restrict__ Vtab,
    float* __restrict__ nvtab)
{
  __shared__ float hs[H];
  __shared__ float ff1[2 * H];
  __shared__ float lns[H];
  const int c = blockIdx.x;
  const int i = threadIdx.x;

  float e = embed[c * H + i];
  hs[i] = e;
  __syncthreads();

  float r1 = b1[i], r2 = b1[i + H];
  for (int j = 0; j < H; ++j) {
    float hj = hs[j];
    r1 = fmaf(W1[i * H + j], hj, r1);
    r2 = fmaf(W1[(i + H) * H + j], hj, r2);
  }
  ff1[i]     = fmaxf(r1, 0.f);
  ff1[i + H] = fmaxf(r2, 0.f);
  __syncthreads();

  float o = b2[i];
  for (int m = 0; m < 2 * H; ++m) o = fmaf(W2[i * 2 * H + m], ff1[m], o);
  float y = e + o;

  float mu  = wave_allsum(y) * (1.f / H);
  float d   = y - mu;
  float var = wave_allsum(d * d) * (1.f / H);
  float ln  = d * (1.f / sqrtf(var + LN_EPS)) * ln_g[i] + ln_b[i];
  lns[i] = ln;
  __syncthreads();
  Htab[c * H + i] = ln;

  float k = 0.f, v = 0.f;
  for (int j = 0; j < H; ++j) {
    float lj = lns[j];
    k = fmaf(Wk[i * H + j], lj, k);
    v = fmaf(Wv[i * H + j], lj, v);
  }
  float nk = sqrtf(wave_allsum(k * k));
  Ktab[c * H + i] = k / fmaxf(nk, 1e-12f);
  Vtab[c * H + i] = v;
  float nv = sqrtf(wave_allsum(v * v));
  if (i == 0) nvtab[c] = 0.4f * nv;   // gate threshold, sqrt domain
}

// ---------------- Kernel B: chunked-WY eager scan (T=8) ----------------
// One block (4 waves) per batch element. Per chunk of 8 steps:
//  - top: load 8 residual rows + thresholds + staged 28-entry in-chunk Gram triangle
//  - 8 register-only gates (accept i: d_i = r_i; r_j -= G[c_i][c_j]*d_i for j>i,
//    chronological) — serial chain per step = fmaf + DPP norm + sqrt + compare
//  - flush: ONE barrier pair; every R row gets read-once + 8 chronological fmaf
//    (d=0 slots exact no-ops) + write-once; M column slices batched the same way.
// All fmaf operands / G values / DPP chains / compares identical to rounds 10-13
// -> bitwise-identical output (absmax must equal 0.001953125).
__global__ __launch_bounds__(256, 1) void scan_kernel(
    const int* __restrict__ x, const float* __restrict__ Htab,
    const float* __restrict__ Ktab, const float* __restrict__ Vtab,
    const float* __restrict__ nvtab,
    const float* __restrict__ Wq, const float* __restrict__ Wr,
    const float* __restrict__ alpha, const float* __restrict__ Wout,
    const float* __restrict__ bout, float* __restrict__ out)
{
  __shared__ float4 Kl4[VOCABN * H / 4];   // khat [c][j]; becomes M_N after scan
  __shared__ float  Gl[VOCABN * H];        // Gram [c][cc]; becomes M_T after scan
  __shared__ float4 Rl4[VOCABN * H / 4];   // residual [c][i]
  __shared__ int    xl[LSEQ];
  __shared__ float4 gin4[NCHUNK * 8];      // per-chunk 28-entry Gram triangle (7 float4 used)
  __shared__ float  thl[VOCABN];
  __shared__ float  hbuf[H];
  __shared__ float  qbuf[H];
  __shared__ float  mbuf[H];
  float* Kl = (float*)Kl4;
  float* Rl = (float*)Rl4;

  const int b    = blockIdx.x;
  const int tid  = threadIdx.x;
  const int lane = tid & 63;
  const int wid  = tid >> 6;

  // ---- stage tables + token row into LDS (256 threads) ----
  {
    const float4* Kg = (const float4*)Ktab;
    const float4* Vg = (const float4*)Vtab;
    for (int q = tid; q < VOCABN * H / 4; q += 256) { Kl4[q] = Kg[q]; Rl4[q] = Vg[q]; }
    const int4* xg = (const int4*)(x + b * LSEQ);
    int4* xl4 = (int4*)xl;
    for (int q = tid; q < LSEQ / 4; q += 256) xl4[q] = xg[q];
    if (tid < VOCABN) thl[tid] = nvtab[tid];
  }
  __syncthreads();

  // ---- Gram in LDS, 16 rows per wave (verbatim rounds 10-13) ----
  {
    float4 kr[16];
#pragma unroll
    for (int q = 0; q < 16; ++q) kr[q] = Kl4[lane * 16 + q];
    for (int r = 0; r < 16; ++r) {
      const int c2 = wid * 16 + r;
      const float4* kp2 = (const float4*)(Kl + c2 * H);
      float a0 = 0.f, a1 = 0.f, a2 = 0.f, a3 = 0.f;
#pragma unroll
      for (int q = 0; q < 16; ++q) {
        float4 kq = kp2[q];
        a0 = fmaf(kr[q].x, kq.x, a0);
        a1 = fmaf(kr[q].y, kq.y, a1);
        a2 = fmaf(kr[q].z, kq.z, a2);
        a3 = fmaf(kr[q].w, kq.w, a3);
      }
      Gl[c2 * H + lane] = (a0 + a1) + (a2 + a3);
    }
  }
  __syncthreads();

  // ---- stage per-chunk in-chunk Gram triangles (static token stream; one-time) ----
  for (int n = tid; n < NCHUNK; n += 256) {
    const int base = n * TCH;
    int ct[8];
#pragma unroll
    for (int i = 0; i < 8; ++i) ct[i] = xl[base + i];
    float* gout = (float*)(gin4 + n * 8);
    int idx = 0;
    for (int i = 0; i < 7; ++i)
      for (int j = i + 1; j < 8; ++j)
        gout[idx++] = Gl[ct[i] * H + ct[j]];
  }
  __syncthreads();

  // M column slice: Mw[q] holds M[lane][wid*16 + 4q .. 4q+3]
  float4 Mw[4];
#pragma unroll
  for (int q = 0; q < 4; ++q) Mw[q] = make_float4(0.f, 0.f, 0.f, 0.f);

  for (int n = 0; n < NCHUNK; ++n) {
    const int base = n * TCH;
    // ---- chunk top: tokens, rows, thresholds, Gram triangle ----
    const int4 t0 = *(const int4*)(xl + base);
    const int4 t1 = *(const int4*)(xl + base + 4);
    int c_[8];
    c_[0] = __builtin_amdgcn_readfirstlane(t0.x);
    c_[1] = __builtin_amdgcn_readfirstlane(t0.y);
    c_[2] = __builtin_amdgcn_readfirstlane(t0.z);
    c_[3] = __builtin_amdgcn_readfirstlane(t0.w);
    c_[4] = __builtin_amdgcn_readfirstlane(t1.x);
    c_[5] = __builtin_amdgcn_readfirstlane(t1.y);
    c_[6] = __builtin_amdgcn_readfirstlane(t1.z);
    c_[7] = __builtin_amdgcn_readfirstlane(t1.w);

    float rr[8], tt[8], dd[8];
#pragma unroll
    for (int i = 0; i < 8; ++i) { rr[i] = Rl[c_[i] * H + lane]; tt[i] = thl[c_[i]]; }

    float gg[28];
    {
      float4 gq[7];
#pragma unroll
      for (int k = 0; k < 7; ++k) gq[k] = gin4[n * 8 + k];
#pragma unroll
      for (int k = 0; k < 28; ++k)
        gg[k] = (k % 4 == 0) ? gq[k / 4].x : (k % 4 == 1) ? gq[k / 4].y
              : (k % 4 == 2) ? gq[k / 4].z : gq[k / 4].w;
    }

    // ---- 8 register-only gates (chronological; bitwise == eager forwarding) ----
#pragma unroll
    for (int i = 0; i < 8; ++i) {
      float nd2 = reduce_to_lane63(rr[i] * rr[i]);
      float nds = sqrtf(rdlf(nd2, 63));
      float thu = __int_as_float(__builtin_amdgcn_readfirstlane(__float_as_int(tt[i])));
      dd[i] = 0.f;
      if (nds > thu) {                     // block-uniform
        dd[i] = rr[i];
#pragma unroll
        for (int j = i + 1; j < 8; ++j)
          rr[j] = fmaf(-gg[i * (15 - i) / 2 + (j - i - 1)], dd[i], rr[j]);
      }
    }

    // ---- flush: one barrier pair per chunk ----
    __syncthreads();                       // read-fence (all waves' row loads done)
    // R RMW: per wave 16 rows; each row read once, 8 chronological fmaf, write once
#pragma unroll
    for (int g = 0; g < 4; ++g) {
      float4 Gq[8];
#pragma unroll
      for (int i = 0; i < 8; ++i)
        Gq[i] = ((const float4*)(Gl + c_[i] * H))[wid * 4 + g];
#pragma unroll
      for (int r = 0; r < 4; ++r) {
        const int cc = wid * 16 + g * 4 + r;
        float val = Rl[cc * H + lane];
#pragma unroll
        for (int i = 0; i < 8; ++i) {
          const float co = (r == 0) ? Gq[i].x : (r == 1) ? Gq[i].y
                         : (r == 2) ? Gq[i].z : Gq[i].w;
          val = fmaf(-co, dd[i], val);     // d=0 slots: exact no-ops
        }
        Rl[cc * H + lane] = val;
      }
    }
    // M column slices: chronological d_0..d_7 per component (== eager order)
#pragma unroll
    for (int q = 0; q < 4; ++q) {
      float4 Kq[8];
#pragma unroll
      for (int i = 0; i < 8; ++i)
        Kq[i] = ((const float4*)(Kl + c_[i] * H))[wid * 4 + q];
#pragma unroll
      for (int i = 0; i < 8; ++i) {
        Mw[q].x = fmaf(dd[i], Kq[i].x, Mw[q].x);
        Mw[q].y = fmaf(dd[i], Kq[i].y, Mw[q].y);
        Mw[q].z = fmaf(dd[i], Kq[i].z, Mw[q].z);
        Mw[q].w = fmaf(dd[i], Kq[i].w, Mw[q].w);
      }
    }
    __syncthreads();                       // write-fence
  }

  // ---- reassemble M: Gl -> M_T (stride H), Kl -> M_N (rounds 12/13 layout) ----
  __syncthreads();
  float* Mt = Gl;                          // Gram dead after scan
#pragma unroll
  for (int r = 0; r < 4; ++r) {
    const int jb = wid * 16 + r * 4;
    float4 m = Mw[r];
    Mt[(jb + 0) * H + lane] = m.x;
    Mt[(jb + 1) * H + lane] = m.y;
    Mt[(jb + 2) * H + lane] = m.z;
    Mt[(jb + 3) * H + lane] = m.w;
    Kl[lane * H + jb + 0] = m.x;
    Kl[lane * H + jb + 1] = m.y;
    Kl[lane * H + jb + 2] = m.z;
    Kl[lane * H + jb + 3] = m.w;
  }
  __syncthreads();

  // ---------------- fused readout: wave 0 (verbatim rounds 12/13, passed) ----------------
  if (wid == 0) {
    const int clast = xl[LSEQ - 1];
    hbuf[lane] = Htab[clast * H + lane];

    float qi = 0.f;
    for (int j = 0; j < H; ++j) qi = fmaf(Wq[lane * H + j], hbuf[j], qi);
    qbuf[lane] = qi;

    float qri = 0.f;
    for (int j = 0; j < H; ++j) qri = fmaf(Wr[lane * H + j], qbuf[j], qri);

    // slot norms^2: lane s reads M_N column s (conflict-free)
    float n2r = 0.f;
    for (int i2 = 0; i2 < H; ++i2) { float m = Kl[i2 * H + lane]; n2r = fmaf(m, m, n2r); }

    // top-8 slots by norm (ties -> smaller index)
    const int KS = 8;
    int idxs[KS];
    float nloc = n2r;
#pragma unroll
    for (int k = 0; k < KS; ++k) {
      float v = nloc; int idx = lane;
#pragma unroll
      for (int s = 1; s < 64; s <<= 1) {
        float ov = __shfl_xor(v, s, 64);
        int   oi = __shfl_xor(idx, s, 64);
        if (ov > v || (ov == v && oi < idx)) { v = ov; idx = oi; }
      }
      idxs[k] = idx;
      if (lane == idx) nloc = -1.f;
    }

    float sel[KS], lg[KS];
#pragma unroll
    for (int k = 0; k < KS; ++k) {
      float s = Mt[idxs[k] * H + lane];     // M_T[idx][lane]
      sel[k] = s;
      lg[k] = wave_allsum(s * qri) * 0.125f;   // / sqrt(64)
    }
    float lmax = lg[0];
#pragma unroll
    for (int k = 1; k < KS; ++k) lmax = fmaxf(lmax, lg[k]);
    float esum = 0.f, retro = 0.f;
#pragma unroll
    for (int k = 0; k < KS; ++k) {
      float e = expf(lg[k] - lmax);
      esum += e;
      retro = fmaf(e, sel[k], retro);
    }
    retro /= esum;

    // m_ctx = M q : lane i, ascending j reading M_T[j][lane] (conflict-free)
    float mc = 0.f;
    for (int j = 0; j < H; ++j) mc = fmaf(Mt[j * H + lane], qbuf[j], mc);

    float a = 1.f / (1.f + expf(-alpha[0]));
    float mixed = fmaxf(fmaf(a, retro, (1.f - a) * mc), 0.f);
    mbuf[lane] = mixed;

    float oo = bout[lane];
    for (int i2 = 0; i2 < H; ++i2) oo = fmaf(Wout[lane * H + i2], mbuf[i2], oo);
    out[b * VOCABN + lane] = oo;
  }
}

extern "C" void kernel_launch(void* const* d_in, const int* in_sizes, int n_in,
                              void* d_out, int out_size, void* d_ws, size_t ws_size,
                              hipStream_t stream) {
  const int*   x     = (const int*)d_in[0];
  const float* embed = (const float*)d_in[1];
  const float* W1    = (const float*)d_in[2];
  const float* b1    = (const float*)d_in[3];
  const float* W2    = (const float*)d_in[4];
  const float* b2    = (const float*)d_in[5];
  const float* ln_g  = (const float*)d_in[6];
  const float* ln_b  = (const float*)d_in[7];
  const float* Wk    = (const float*)d_in[8];
  const float* Wv    = (const float*)d_in[9];
  const float* Wq    = (const float*)d_in[10];
  const float* Wr    = (const float*)d_in[11];
  const float* alpha = (const float*)d_in[12];
  const float* Wout  = (const float*)d_in[13];
  const float* bout  = (const float*)d_in[14];
  float* out = (float*)d_out;

  const int B = in_sizes[0] / LSEQ;

  float* ws    = (float*)d_ws;
  float* Htab  = ws;          // 4096
  float* Ktab  = ws + 4096;   // 4096
  float* Vtab  = ws + 8192;   // 4096
  float* nvtab = ws + 12288;  // 64

  tables_kernel<<<VOCABN, 64, 0, stream>>>(embed, W1, b1, W2, b2, ln_g, ln_b,
                                           Wk, Wv, Htab, Ktab, Vtab, nvtab);
  scan_kernel<<<B, 256, 0, stream>>>(x, Htab, Ktab, Vtab, nvtab,
                                     Wq, Wr, alpha, Wout, bout, out);
}